// Round 8
// baseline (211.532 us; speedup 1.0000x reference)
//
#include <hip/hip_runtime.h>
#include <hip/hip_bf16.h>
#include <stdint.h>

#define B_ 2048
#define L_ 128
#define V_ 50000
#define D_ 128

typedef __attribute__((ext_vector_type(8))) short bf16x8;
typedef __attribute__((ext_vector_type(8))) unsigned short ushort8;
typedef __attribute__((ext_vector_type(4))) float f32x4;

__device__ inline unsigned short f2bf(float f) {
    union { float f; uint32_t u; } v; v.f = f;
    uint32_t u = v.u + 0x7FFFu + ((v.u >> 16) & 1u);   // RNE
    return (unsigned short)(u >> 16);
}
__device__ inline float bf2f(unsigned short h) {
    union { uint32_t u; float f; } v; v.u = ((uint32_t)h) << 16;
    return v.f;
}
__device__ inline float tanh_fast(float x) {
    float xc = fminf(fmaxf(x, -15.f), 15.f);
    float z = __expf(2.f * xc);
    return (z - 1.f) / (z + 1.f);
}
// load 8 fp32 -> bf16x8 (fallback path only)
__device__ inline bf16x8 ld8f(const float* p) {
    float4 x0 = *(const float4*)p;
    float4 x1 = *(const float4*)(p + 4);
    ushort8 v;
    v[0] = f2bf(x0.x); v[1] = f2bf(x0.y); v[2] = f2bf(x0.z); v[3] = f2bf(x0.w);
    v[4] = f2bf(x1.x); v[5] = f2bf(x1.y); v[6] = f2bf(x1.z); v[7] = f2bf(x1.w);
    union { ushort8 u; bf16x8 b; } c; c.u = v; return c.b;
}

// ---------------- kernel 0: aT_bf16[n][d] = bf16(attn_a[d][n]) ----------------
__global__ __launch_bounds__(256) void k_prep(const float* __restrict__ a,
                                              unsigned short* __restrict__ aT) {
    int i = blockIdx.x * 256 + threadIdx.x;   // 16384 elems
    int d = i >> 7, n = i & 127;
    aT[n * 128 + d] = f2bf(a[d * 128 + n]);
}

// ---------------- kernel 0b: emb_bf[v][d] = bf16(emb[v][d]) ----------------
__global__ __launch_bounds__(256) void k_convE(const float* __restrict__ emb,
                                               unsigned short* __restrict__ emb_bf) {
    size_t i = ((size_t)blockIdx.x * 256 + threadIdx.x) * 8;  // 6,400,000 elems, grid exact
    float4 x0 = *(const float4*)(emb + i);
    float4 x1 = *(const float4*)(emb + i + 4);
    ushort8 v;
    v[0] = f2bf(x0.x); v[1] = f2bf(x0.y); v[2] = f2bf(x0.z); v[3] = f2bf(x0.w);
    v[4] = f2bf(x1.x); v[5] = f2bf(x1.y); v[6] = f2bf(x1.z); v[7] = f2bf(x1.w);
    *(ushort8*)(emb_bf + i) = v;
}

// ---------------- kernel 1: user_bf16[b][d]  (unchanged) ----------------
__global__ __launch_bounds__(256) void k_user(
    const int* __restrict__ ids, const int* __restrict__ msk,
    const float* __restrict__ emb, const unsigned short* __restrict__ emb_bf,
    const unsigned short* __restrict__ aT,
    const float* __restrict__ bvec, unsigned short* __restrict__ user_bf,
    int use_bf) {
    __shared__ __align__(16) unsigned short lh[128 * 128];  // h tile, swizzled (32KB)
    __shared__ float l_e[128];
    __shared__ float l_attn[128];
    __shared__ float l_p[256];

    int b = blockIdx.x;
    int t = threadIdx.x;

    {
        int row = t >> 1, half = t & 1;
        int id = ids[b * L_ + row];
        if (use_bf) {
            const unsigned short* src = emb_bf + (size_t)id * D_ + half * 64;
#pragma unroll
            for (int q = 0; q < 8; ++q) {
                ushort8 v = *(const ushort8*)(src + q * 8);
                int c = half * 64 + q * 8;
                *(ushort8*)&lh[row * 128 + (c ^ ((row & 7) << 3))] = v;
            }
        } else {
            const float* src = emb + (size_t)id * D_ + half * 64;
#pragma unroll
            for (int q = 0; q < 8; ++q) {
                float4 x0 = *(const float4*)(src + q * 8);
                float4 x1 = *(const float4*)(src + q * 8 + 4);
                ushort8 v;
                v[0] = f2bf(x0.x); v[1] = f2bf(x0.y); v[2] = f2bf(x0.z); v[3] = f2bf(x0.w);
                v[4] = f2bf(x1.x); v[5] = f2bf(x1.y); v[6] = f2bf(x1.z); v[7] = f2bf(x1.w);
                int c = half * 64 + q * 8;
                *(ushort8*)&lh[row * 128 + (c ^ ((row & 7) << 3))] = v;
            }
        }
    }
    __syncthreads();

    int wave = t >> 6, lane = t & 63, lo = lane & 15, hi = lane >> 4;

    f32x4 acc[2][8] = {};
#pragma unroll
    for (int kk = 0; kk < 4; ++kk) {
        int kc = kk * 32 + hi * 8;
        bf16x8 afr[2];
#pragma unroll
        for (int mi = 0; mi < 2; ++mi) {
            int row = wave * 32 + mi * 16 + lo;
            afr[mi] = *(const bf16x8*)&lh[row * 128 + (kc ^ ((row & 7) << 3))];
        }
#pragma unroll
        for (int nj = 0; nj < 8; ++nj) {
            int col = nj * 16 + lo;
            bf16x8 bfr = *(const bf16x8*)(aT + col * 128 + kc);
            acc[0][nj] = __builtin_amdgcn_mfma_f32_16x16x32_bf16(afr[0], bfr, acc[0][nj], 0, 0, 0);
            acc[1][nj] = __builtin_amdgcn_mfma_f32_16x16x32_bf16(afr[1], bfr, acc[1][nj], 0, 0, 0);
        }
    }

    float bv[8];
#pragma unroll
    for (int nj = 0; nj < 8; ++nj) bv[nj] = bvec[nj * 16 + lo];
#pragma unroll
    for (int mi = 0; mi < 2; ++mi) {
#pragma unroll
        for (int reg = 0; reg < 4; ++reg) {
            float p = 0.f;
#pragma unroll
            for (int nj = 0; nj < 8; ++nj) p += tanh_fast(acc[mi][nj][reg]) * bv[nj];
            p += __shfl_xor(p, 1); p += __shfl_xor(p, 2);
            p += __shfl_xor(p, 4); p += __shfl_xor(p, 8);
            int row = wave * 32 + mi * 16 + hi * 4 + reg;
            if (lo == 0) l_e[row] = p;
        }
    }
    __syncthreads();

    if (t < 128) {
        float e = l_e[t];
        float at = 0.f;
        if (msk[b * L_ + t]) at = 1.f / (1.f + __expf(-e));
        l_attn[t] = at;
    }
    __syncthreads();

    {
        int d = t & 127, half = t >> 7;
        float s = 0.f;
#pragma unroll 8
        for (int l = half * 64; l < half * 64 + 64; ++l)
            s += l_attn[l] * bf2f(lh[l * 128 + (d ^ ((l & 7) << 3))]);
        l_p[t] = s;
    }
    __syncthreads();
    if (t < 128) {
        float u = l_p[t] + l_p[t + 128];
        user_bf[b * 128 + t] = f2bf(u);
    }
}

// ---------------- kernel 2: logits = user_bf16 @ emb^T + bias ----------------
// R7 structure + SOFTWARE-PIPELINED user loads (1 chunk ahead, issued at TOP of
// the loop body, BEFORE this chunk's stores enter the vmem queue). vmcnt is a
// FIFO over loads AND stores: with loads older than the stores, the operand
// wait becomes vmcnt(8) (stores may stay outstanding) instead of a full store
// drain. Stores retire asynchronously -> store-BW-bound, not store-latency.
__global__ __launch_bounds__(256) void k_logits(
    const unsigned short* __restrict__ user_bf, const float* __restrict__ emb,
    const unsigned short* __restrict__ emb_bf,
    const float* __restrict__ bias, float* __restrict__ out, int use_bf) {
    __shared__ __align__(16) float lt[4][32 * 64];   // per-wave C-tile (32KB total)

    int t = threadIdx.x;
    int wave = t >> 6, lane = t & 63, lo = lane & 15, hi = lane >> 4;
    int n0 = blockIdx.x * 64;   // 782 blocks * 64 cols = 50048 >= V_

    // emb A-fragments for the block's 64 cols, resident all kernel (64 VGPR)
    bf16x8 efr[4][4];
#pragma unroll
    for (int cg = 0; cg < 4; ++cg) {
        int col = n0 + cg * 16 + lo;
        int cc = (col < V_) ? col : 0;          // emb row 0 is all zeros
        const unsigned short* ep = emb_bf + (size_t)cc * 128 + hi * 8;
        if (use_bf) {
#pragma unroll
            for (int kk = 0; kk < 4; ++kk)
                efr[cg][kk] = *(const bf16x8*)(ep + kk * 32);
        } else {
            const float* ef = emb + (size_t)cc * 128 + hi * 8;
#pragma unroll
            for (int kk = 0; kk < 4; ++kk)
                efr[cg][kk] = ld8f(ef + kk * 32);
        }
    }

    // bias: n = n0 + cg*16 + hi*4 + reg
    float4 bb[4];
#pragma unroll
    for (int cg = 0; cg < 4; ++cg) {
        int n = n0 + cg * 16 + hi * 4;
        if (n + 3 < V_) {
            bb[cg] = *(const float4*)(bias + n);
        } else {
            bb[cg].x = (n + 0 < V_) ? bias[n + 0] : 0.f;
            bb[cg].y = (n + 1 < V_) ? bias[n + 1] : 0.f;
            bb[cg].z = (n + 2 < V_) ? bias[n + 2] : 0.f;
            bb[cg].w = (n + 3 < V_) ? bias[n + 3] : 0.f;
        }
    }

    float* myt = lt[wave];

    // prologue: preload user fragments for this wave's first chunk
    bf16x8 ufr[2][4], ufn[2][4];
    {
        int rbase = wave * 32;
#pragma unroll
        for (int mi = 0; mi < 2; ++mi) {
            const unsigned short* up = user_bf + (size_t)(rbase + mi * 16 + lo) * 128 + hi * 8;
#pragma unroll
            for (int kk = 0; kk < 4; ++kk)
                ufr[mi][kk] = *(const bf16x8*)(up + kk * 32);
        }
    }

    // 16 row-chunks of 32 per wave (chunks wave, wave+4, ...)
#pragma unroll 1
    for (int ci = 0; ci < 16; ++ci) {
        int c = wave + ci * 4;
        int rbase = c * 32;

        // ---- issue NEXT chunk's loads FIRST (before this chunk's stores)
        int cn = c + 4;
        if (cn > 63) cn = wave;              // harmless wrap (redundant reload)
        int rnext = cn * 32;
#pragma unroll
        for (int mi = 0; mi < 2; ++mi) {
            const unsigned short* up = user_bf + (size_t)(rnext + mi * 16 + lo) * 128 + hi * 8;
#pragma unroll
            for (int kk = 0; kk < 4; ++kk)
                ufn[mi][kk] = *(const bf16x8*)(up + kk * 32);
        }

        // ---- MFMA with current fragments (operands loaded BEFORE older stores)
        f32x4 acc[4][2] = {};   // [cg][mi]
#pragma unroll
        for (int kk = 0; kk < 4; ++kk)
#pragma unroll
            for (int cg = 0; cg < 4; ++cg)
#pragma unroll
                for (int mi = 0; mi < 2; ++mi)
                    // D[row=hi*4+reg -> vocab col][col=lo -> batch row]
                    acc[cg][mi] = __builtin_amdgcn_mfma_f32_16x16x32_bf16(
                        efr[cg][kk], ufr[mi][kk], acc[cg][mi], 0, 0, 0);

        // ---- epilogue A: acc+bias -> LDS tile [b_loc][n_loc], chunk-XOR swizzle
#pragma unroll
        for (int mi = 0; mi < 2; ++mi) {
            int b_loc = mi * 16 + lo;
#pragma unroll
            for (int cg = 0; cg < 4; ++cg) {
                f32x4 o;
                o[0] = acc[cg][mi][0] + bb[cg].x;
                o[1] = acc[cg][mi][1] + bb[cg].y;
                o[2] = acc[cg][mi][2] + bb[cg].z;
                o[3] = acc[cg][mi][3] + bb[cg].w;
                int ch = (cg * 4 + hi) ^ (b_loc & 15);
                *(f32x4*)&myt[b_loc * 64 + ch * 4] = o;
            }
        }

        // ---- epilogue B: dense read-back + full-line stores
#pragma unroll
        for (int it = 0; it < 8; ++it) {
            int b_loc = it * 4 + hi;
            f32x4 v = *(const f32x4*)&myt[b_loc * 64 + ((lo ^ (b_loc & 15)) * 4)];
            int n = n0 + lo * 4;
            if (n + 3 < V_) {
                *(f32x4*)(out + (size_t)(rbase + b_loc) * V_ + n) = v;
            }
        }

        // ---- rotate prefetched fragments into place
#pragma unroll
        for (int mi = 0; mi < 2; ++mi)
#pragma unroll
            for (int kk = 0; kk < 4; ++kk)
                ufr[mi][kk] = ufn[mi][kk];
    }
}

extern "C" void kernel_launch(void* const* d_in, const int* in_sizes, int n_in,
                              void* d_out, int out_size, void* d_ws, size_t ws_size,
                              hipStream_t stream) {
    const int* ids      = (const int*)d_in[0];
    const int* msk      = (const int*)d_in[1];
    const float* emb    = (const float*)d_in[2];
    const float* attn_a = (const float*)d_in[3];
    const float* attn_b = (const float*)d_in[4];
    const float* rbias  = (const float*)d_in[5];
    float* out = (float*)d_out;

    unsigned short* aT      = (unsigned short*)d_ws;                     // 32 KB
    unsigned short* user_bf = (unsigned short*)((char*)d_ws + 32768);    // 512 KB
    unsigned short* emb_bf  = (unsigned short*)((char*)d_ws + 32768 + 524288);  // 12.8 MB
    int use_bf = (ws_size >= (size_t)(32768 + 524288 + 12800000)) ? 1 : 0;

    k_prep<<<64, 256, 0, stream>>>(attn_a, aT);
    if (use_bf) k_convE<<<3125, 256, 0, stream>>>(emb, emb_bf);
    k_user<<<2048, 256, 0, stream>>>(ids, msk, emb, emb_bf, aT, attn_b, user_bf, use_bf);
    k_logits<<<782, 256, 0, stream>>>(user_bf, emb, emb_bf, rbias, out, use_bf);
}